// Round 20
// baseline (333.812 us; speedup 1.0000x reference)
//
#include <hip/hip_runtime.h>
#include <hip/hip_bf16.h>

#define B_   4
#define DENC 512
#define T_   200
#define DDEC 640
#define U_   100
#define H_   640
#define V_   1025

typedef float f32x4 __attribute__((ext_vector_type(4)));
typedef _Float16 f16x8 __attribute__((ext_vector_type(8)));

// relu(e+d) on 8 packed fp16: 4x v_pk_add_f16 + 4x v_pk_max_f16
__device__ __forceinline__ uint4 addrelu16(uint4 e, uint4 d) {
    f16x8 ev = __builtin_bit_cast(f16x8, e);
    f16x8 dv = __builtin_bit_cast(f16x8, d);
    f16x8 s = ev + dv;
    f16x8 z = {(_Float16)0.f, (_Float16)0.f, (_Float16)0.f, (_Float16)0.f,
               (_Float16)0.f, (_Float16)0.f, (_Float16)0.f, (_Float16)0.f};
    s = __builtin_elementwise_max(s, z);
    return __builtin_bit_cast(uint4, s);
}

__device__ __forceinline__ void gload_lds16(const void* g, void* l) {
    __builtin_amdgcn_global_load_lds(
        (const __attribute__((address_space(1))) unsigned int*)g,
        (__attribute__((address_space(3))) unsigned int*)l, 16, 0, 0);
}

// ---------------- K1: fused prep (r13/r18-proven), fp16 outputs
__global__ __launch_bounds__(256) void prep_fused_kernel(
    const float* __restrict__ enc, const float* __restrict__ W_enc,
    const float* __restrict__ b_enc,
    const float* __restrict__ dec, const float* __restrict__ W_pred,
    const float* __restrict__ b_pred,
    const float* __restrict__ W_out,
    _Float16* __restrict__ encP, _Float16* __restrict__ decP,
    _Float16* __restrict__ Wt)
{
    __shared__ float tile[64][65];
    int bx = blockIdx.x;
    int tid = threadIdx.x;

    if (bx < 260) {
        int b = bx / 65, r5 = bx % 65, hc = r5 / 13, tg = r5 % 13;
        int h  = hc * 128 + (tid & 127);
        int t0 = tg * 16 + (tid >> 7) * 8;
        if (t0 >= T_) return;
        const float* ec = enc + (size_t)b * DENC * T_ + t0;
        const float* Wc = W_enc + h;
        float acc[8] = {0.f,0.f,0.f,0.f,0.f,0.f,0.f,0.f};
        #pragma unroll 8
        for (int d = 0; d < DENC; ++d) {
            float w = Wc[(size_t)d * H_];
            float4 e0 = *(const float4*)(ec + (size_t)d * T_);
            float4 e1 = *(const float4*)(ec + (size_t)d * T_ + 4);
            acc[0] += w * e0.x; acc[1] += w * e0.y; acc[2] += w * e0.z; acc[3] += w * e0.w;
            acc[4] += w * e1.x; acc[5] += w * e1.y; acc[6] += w * e1.z; acc[7] += w * e1.w;
        }
        float bb = b_enc[h];
        #pragma unroll
        for (int i = 0; i < 8; ++i)
            encP[((size_t)b * T_ + t0 + i) * H_ + h] = (_Float16)(acc[i] + bb);
    } else if (bx < 520) {
        int i5 = bx - 260;
        int b = i5 / 65, r5 = i5 % 65, hc = r5 / 13, ug = r5 % 13;
        int h  = hc * 128 + (tid & 127);
        int u0 = ug * 8 + (tid >> 7) * 4;
        if (u0 >= U_) return;
        const float* dc = dec + (size_t)b * DDEC * U_ + u0;
        const float* Wc = W_pred + h;
        float acc[4] = {0.f,0.f,0.f,0.f};
        #pragma unroll 8
        for (int d = 0; d < DDEC; ++d) {
            float w = Wc[(size_t)d * H_];
            float4 e0 = *(const float4*)(dc + (size_t)d * U_);
            acc[0] += w * e0.x; acc[1] += w * e0.y; acc[2] += w * e0.z; acc[3] += w * e0.w;
        }
        float bb = b_pred[h];
        #pragma unroll
        for (int i = 0; i < 4; ++i)
            decP[((size_t)b * U_ + u0 + i) * H_ + h] = (_Float16)(acc[i] + bb);
    } else {
        int j = bx - 520;
        int hc = j / 18, vc = j % 18;
        int h0 = hc * 64, v0 = vc * 64;
        #pragma unroll
        for (int it = 0; it < 16; ++it) {
            int hl = it * 4 + (tid >> 6);
            int vl = tid & 63;
            int v = v0 + vl;
            tile[hl][vl] = (v < V_) ? W_out[(size_t)(h0 + hl) * V_ + v] : 0.f;
        }
        __syncthreads();
        #pragma unroll
        for (int it = 0; it < 16; ++it) {
            int vl = it * 4 + (tid >> 6);
            int hl = tid & 63;
            Wt[(size_t)(v0 + vl) * H_ + h0 + hl] = (_Float16)tile[hl][vl];
        }
    }
}

// ---------------- K4: r6 resurrection (offsets fixed) — B-full-K-in-LDS, barrier-free K-loop
// 512 thr = 8 waves; block = 256 rows (32t x 8u) x 64 v-cols; wave = 32 rows x 64 cols.
// B (64x640 fp16 = 80KB) staged ONCE via gload (XOR swizzle), ONE barrier, then 20 K-steps
// with zero barriers / zero in-loop gloads: A built in regs (2-deep L2 prefetch).
// Epilogue: r17-style wave-private LDS transpose -> 256B-contiguous scalar stores.
// blocks [0,5824): GEMM (XCD-swizzled). blocks [5824,5981): v=1024 column.
__global__ __launch_bounds__(512, 4) void joint_kernel(
    const unsigned short* __restrict__ encP,   // [B,T,H] fp16
    const unsigned short* __restrict__ decP,   // [B,U,H] fp16
    const unsigned short* __restrict__ Wt,     // [V][H] fp16 (only v<1025 used)
    const float* __restrict__ b_out,           // [V]
    float* __restrict__ out)                   // [B,T,U,V] f32
{
    extern __shared__ char LDSRAW[];           // 80 KB dynamic
    int tid = threadIdx.x;

    if (blockIdx.x >= 5824) {
        // ---- fused lastcol: v = 1024 (512-thread blocks)
        int idx = (blockIdx.x - 5824) * 512 + tid;
        if (idx >= B_ * T_ * U_) return;
        int u = idx % U_;
        int t = (idx / U_) % T_;
        int b = idx / (U_ * T_);
        const uint4* e = (const uint4*)(encP + ((size_t)b * T_ + t) * H_);
        const uint4* d = (const uint4*)(decP + ((size_t)b * U_ + u) * H_);
        const uint4* wv = (const uint4*)(Wt + (size_t)1024 * H_);
        float acc1 = 0.f;
        for (int c = 0; c < H_ / 8; ++c) {
            f16x8 x = __builtin_bit_cast(f16x8, addrelu16(e[c], d[c]));
            f16x8 wq = __builtin_bit_cast(f16x8, wv[c]);
            #pragma unroll
            for (int m = 0; m < 8; ++m)
                acc1 += (float)x[m] * (float)wq[m];
        }
        out[((size_t)(b * T_ + t) * U_ + u) * V_ + 1024] = acc1 + b_out[1024];
        return;
    }

    // ---- XCD swizzle: f -> n = (f&7)*728 + (f>>3); n = vblk*364 + b*91 + y
    int f    = blockIdx.x;                     // 0..5823
    int n    = (f & 7) * 728 + (f >> 3);
    int vblk = n / 364;
    int rem  = n - vblk * 364;
    int b    = rem / 91;
    int y    = rem - b * 91;
    int tt = y / 13, ut = y % 13;
    int t0 = tt * 32, u0 = ut * 8;
    int vb = vblk * 64;
    int lane = tid & 63, w = tid >> 6;
    int lrow = lane & 15, kg = lane >> 4;

    // ---- stage B once: wave w covers local cols 8w..8w+7 (10 gloads of 16B x 64 lanes)
    {
        char* ldsb = LDSRAW + w * 10240;
        #pragma unroll
        for (int m = 0; m < 10; ++m) {
            int flat = m * 64 + lane;
            int cl = flat / 80, p = flat % 80;          // local col (0..7), phys chunk
            int c  = p ^ (cl & 7);                      // logical chunk at phys slot p
            const unsigned short* src = Wt + (size_t)(vb + w * 8 + cl) * H_ + c * 8;
            gload_lds16(src, ldsb + m * 1024);
        }
    }
    __syncthreads();   // B resident for the whole K-loop (barrier #1 of 2+epilogue)

    // ---- A row mapping (wave-local 32 rows = 4t x 8u): i=0 rows w*32+lrow, i=1 +16
    int row0 = w * 32 + lrow;
    int tA0 = t0 + (row0 >> 3);        if (tA0 > T_ - 1) tA0 = T_ - 1;
    int tA1 = t0 + ((row0 + 16) >> 3); if (tA1 > T_ - 1) tA1 = T_ - 1;
    int uA  = u0 + (lrow & 7);         if (uA  > U_ - 1) uA  = U_ - 1;
    const uint4* e0p = (const uint4*)(encP + ((size_t)b * T_ + tA0) * H_) + kg;
    const uint4* e1p = (const uint4*)(encP + ((size_t)b * T_ + tA1) * H_) + kg;
    const uint4* dp  = (const uint4*)(decP + ((size_t)b * U_ + uA ) * H_) + kg;

    // ---- B read bases: col = j*16+lrow; byte = col*1280 + (((ks*4+kg)^(col&7))<<4)
    const char* LBb = LDSRAW;
    int sB = (lrow & 7) << 4;
    int bbase[4];
    #pragma unroll
    for (int j = 0; j < 4; ++j) bbase[j] = (j * 16 + lrow) * 1280;

    f32x4 acc[2][4];
    #pragma unroll
    for (int i = 0; i < 2; ++i)
        #pragma unroll
        for (int j = 0; j < 4; ++j)
            acc[i][j] = (f32x4){0.f, 0.f, 0.f, 0.f};

    // ---- 2-deep E/D prefetch registers
    uint4 E0a = e0p[0], E1a = e1p[0], Da = dp[0];
    uint4 E0b = e0p[4], E1b = e1p[4], Db = dp[4];

    // ---- main K loop: 20 steps of K=32, NO barriers, NO in-loop gloads
    #pragma unroll 2
    for (int ks = 0; ks < 20; ++ks) {
        f16x8 a0 = __builtin_bit_cast(f16x8, addrelu16(E0a, Da));
        f16x8 a1 = __builtin_bit_cast(f16x8, addrelu16(E1a, Da));
        E0a = E0b; E1a = E1b; Da = Db;
        if (ks < 18) {
            E0b = e0p[(ks + 2) * 4];
            E1b = e1p[(ks + 2) * 4];
            Db  = dp[(ks + 2) * 4];
        }
        int xoff = ((ks * 4 + kg) << 4) ^ sB;
        f16x8 bq[4];
        #pragma unroll
        for (int j = 0; j < 4; ++j)
            bq[j] = *(const f16x8*)(LBb + bbase[j] + xoff);
        #pragma unroll
        for (int j = 0; j < 4; ++j) {
            acc[0][j] = __builtin_amdgcn_mfma_f32_16x16x32_f16(a0, bq[j], acc[0][j], 0, 0, 0);
            acc[1][j] = __builtin_amdgcn_mfma_f32_16x16x32_f16(a1, bq[j], acc[1][j], 0, 0, 0);
        }
    }

    // ---- epilogue: wave-private LDS transpose (16x68 f32 per wave) -> contiguous stores
    __syncthreads();   // all waves done reading LB before overwrite
    float* etile = (float*)LDSRAW + (size_t)w * 1088;   // 16*68 f32 = 4352 B per wave
    #pragma unroll
    for (int i = 0; i < 2; ++i) {
        #pragma unroll
        for (int j = 0; j < 4; ++j) {
            int col = j * 16 + lrow;
            float bo = b_out[vb + col];
            #pragma unroll
            for (int q = 0; q < 4; ++q)
                etile[(kg * 4 + q) * 68 + col] = acc[i][j][q] + bo;   // 2 lanes/bank
        }
        __syncthreads();
        #pragma unroll
        for (int rr = 0; rr < 16; ++rr) {
            int row = w * 32 + i * 16 + rr;
            int t = t0 + (row >> 3);
            int u = u0 + (row & 7);
            if (t < T_ && u < U_)
                out[(((size_t)b * T_ + t) * U_ + u) * V_ + vb + lane] = etile[rr * 68 + lane];
        }
        __syncthreads();   // WAR before next i-phase write
    }
}

extern "C" void kernel_launch(void* const* d_in, const int* in_sizes, int n_in,
                              void* d_out, int out_size, void* d_ws, size_t ws_size,
                              hipStream_t stream) {
    const float* enc    = (const float*)d_in[0];
    const float* dec    = (const float*)d_in[1];
    const float* W_enc  = (const float*)d_in[2];
    const float* b_enc  = (const float*)d_in[3];
    const float* W_pred = (const float*)d_in[4];
    const float* b_pred = (const float*)d_in[5];
    const float* W_out  = (const float*)d_in[6];
    const float* b_out  = (const float*)d_in[7];
    float* out = (float*)d_out;

    // fp16 buffers: encP 512,000 elems = 1,024,000 B (the r6/r7 bug was 512,000 B here)
    char* ws = (char*)d_ws;
    _Float16* encP = (_Float16*)ws;                        // 1,024,000 B
    _Float16* decP = (_Float16*)(ws + 1024000);            //   512,000 B
    _Float16* Wt   = (_Float16*)(ws + 1024000 + 512000);   // 1,312,000 B (1025*640*2)

    (void)hipFuncSetAttribute((const void*)joint_kernel,
                              hipFuncAttributeMaxDynamicSharedMemorySize, 81920);

    prep_fused_kernel<<<dim3(700), 256, 0, stream>>>(
        enc, W_enc, b_enc, dec, W_pred, b_pred, W_out, encP, decP, Wt);
    joint_kernel<<<dim3(5824 + 157), 512, 81920, stream>>>(
        (const unsigned short*)encP, (const unsigned short*)decP,
        (const unsigned short*)Wt, b_out, out);
}

// Round 21
// 270.793 us; speedup vs baseline: 1.2327x; 1.2327x over previous
//
#include <hip/hip_runtime.h>
#include <hip/hip_bf16.h>

#define B_   4
#define DENC 512
#define T_   200
#define DDEC 640
#define U_   100
#define H_   640
#define V_   1025
#define VPAD 1152

typedef float f32x4 __attribute__((ext_vector_type(4)));
typedef _Float16 f16x8 __attribute__((ext_vector_type(8)));
typedef unsigned short u16x8 __attribute__((ext_vector_type(8)));

// relu(e+d) on 8 packed fp16: 4x v_pk_add_f16 + 4x v_pk_max_f16
__device__ __forceinline__ uint4 addrelu16(uint4 e, uint4 d) {
    f16x8 ev = __builtin_bit_cast(f16x8, e);
    f16x8 dv = __builtin_bit_cast(f16x8, d);
    f16x8 s = ev + dv;
    f16x8 z = {(_Float16)0.f, (_Float16)0.f, (_Float16)0.f, (_Float16)0.f,
               (_Float16)0.f, (_Float16)0.f, (_Float16)0.f, (_Float16)0.f};
    s = __builtin_elementwise_max(s, z);
    return __builtin_bit_cast(uint4, s);
}

__device__ __forceinline__ void gload_lds16(const void* g, void* l) {
    __builtin_amdgcn_global_load_lds(
        (const __attribute__((address_space(1))) unsigned int*)g,
        (__attribute__((address_space(3))) unsigned int*)l, 16, 0, 0);
}

// ---------------- K1: fused prep (r13-proven structure), fp16 outputs
__global__ __launch_bounds__(256) void prep_fused_kernel(
    const float* __restrict__ enc, const float* __restrict__ W_enc,
    const float* __restrict__ b_enc,
    const float* __restrict__ dec, const float* __restrict__ W_pred,
    const float* __restrict__ b_pred,
    const float* __restrict__ W_out,
    _Float16* __restrict__ encP, _Float16* __restrict__ decP,
    _Float16* __restrict__ Wt)
{
    __shared__ float tile[64][65];
    int bx = blockIdx.x;
    int tid = threadIdx.x;

    if (bx < 260) {
        int b = bx / 65, r5 = bx % 65, hc = r5 / 13, tg = r5 % 13;
        int h  = hc * 128 + (tid & 127);
        int t0 = tg * 16 + (tid >> 7) * 8;
        if (t0 >= T_) return;
        const float* ec = enc + (size_t)b * DENC * T_ + t0;
        const float* Wc = W_enc + h;
        float acc[8] = {0.f,0.f,0.f,0.f,0.f,0.f,0.f,0.f};
        #pragma unroll 8
        for (int d = 0; d < DENC; ++d) {
            float w = Wc[(size_t)d * H_];
            float4 e0 = *(const float4*)(ec + (size_t)d * T_);
            float4 e1 = *(const float4*)(ec + (size_t)d * T_ + 4);
            acc[0] += w * e0.x; acc[1] += w * e0.y; acc[2] += w * e0.z; acc[3] += w * e0.w;
            acc[4] += w * e1.x; acc[5] += w * e1.y; acc[6] += w * e1.z; acc[7] += w * e1.w;
        }
        float bb = b_enc[h];
        #pragma unroll
        for (int i = 0; i < 8; ++i)
            encP[((size_t)b * T_ + t0 + i) * H_ + h] = (_Float16)(acc[i] + bb);
    } else if (bx < 520) {
        int i5 = bx - 260;
        int b = i5 / 65, r5 = i5 % 65, hc = r5 / 13, ug = r5 % 13;
        int h  = hc * 128 + (tid & 127);
        int u0 = ug * 8 + (tid >> 7) * 4;
        if (u0 >= U_) return;
        const float* dc = dec + (size_t)b * DDEC * U_ + u0;
        const float* Wc = W_pred + h;
        float acc[4] = {0.f,0.f,0.f,0.f};
        #pragma unroll 8
        for (int d = 0; d < DDEC; ++d) {
            float w = Wc[(size_t)d * H_];
            float4 e0 = *(const float4*)(dc + (size_t)d * U_);
            acc[0] += w * e0.x; acc[1] += w * e0.y; acc[2] += w * e0.z; acc[3] += w * e0.w;
        }
        float bb = b_pred[h];
        #pragma unroll
        for (int i = 0; i < 4; ++i)
            decP[((size_t)b * U_ + u0 + i) * H_ + h] = (_Float16)(acc[i] + bb);
    } else {
        int j = bx - 520;
        int hc = j / 18, vc = j % 18;
        int h0 = hc * 64, v0 = vc * 64;
        #pragma unroll
        for (int it = 0; it < 16; ++it) {
            int hl = it * 4 + (tid >> 6);
            int vl = tid & 63;
            int v = v0 + vl;
            tile[hl][vl] = (v < V_) ? W_out[(size_t)(h0 + hl) * V_ + v] : 0.f;
        }
        __syncthreads();
        #pragma unroll
        for (int it = 0; it < 16; ++it) {
            int vl = it * 4 + (tid >> 6);
            int hl = tid & 63;
            Wt[(size_t)(v0 + vl) * H_ + h0 + hl] = (_Float16)tile[hl][vl];
        }
    }
}

// ---------------- K4: r18 champion joint (proven 200us): r8 2-phase skeleton, fp16
// operands, LDS-transpose epilogue (256B-contiguous scalar stores), XCD swizzle.
// blocks [0,5200): GEMM tiles.  blocks [5200,5513): v=1024 column.
#define ESTR 260
__global__ __launch_bounds__(256) void joint_kernel(
    const unsigned short* __restrict__ encP,   // [B,T,H] fp16
    const unsigned short* __restrict__ decP,   // [B,U,H] fp16
    const unsigned short* __restrict__ Wt,     // [VPAD][H] fp16
    const float* __restrict__ b_out,           // [V]
    float* __restrict__ out)                   // [B,T,U,V] f32
{
    __shared__ uint4 LA[2][64][4];             // 8 KB
    __shared__ uint4 LB[2][256][4];            // 32 KB
    int tid = threadIdx.x;

    if (blockIdx.x >= 5200) {
        // ---- fused lastcol: v = 1024
        int idx = (blockIdx.x - 5200) * 256 + tid;
        if (idx >= B_ * T_ * U_) return;
        int u = idx % U_;
        int t = (idx / U_) % T_;
        int b = idx / (U_ * T_);
        const uint4* e = (const uint4*)(encP + ((size_t)b * T_ + t) * H_);
        const uint4* d = (const uint4*)(decP + ((size_t)b * U_ + u) * H_);
        const uint4* wv = (const uint4*)(Wt + (size_t)1024 * H_);
        float acc1 = 0.f;
        for (int c = 0; c < H_ / 8; ++c) {
            f16x8 x = __builtin_bit_cast(f16x8, addrelu16(e[c], d[c]));
            f16x8 wq = __builtin_bit_cast(f16x8, wv[c]);
            #pragma unroll
            for (int m = 0; m < 8; ++m)
                acc1 += (float)x[m] * (float)wq[m];
        }
        out[((size_t)(b * T_ + t) * U_ + u) * V_ + 1024] = acc1 + b_out[1024];
        return;
    }

    // ---- XCD swizzle over the 5200 GEMM blocks: f -> n = (f&7)*650 + (f>>3)
    int f   = blockIdx.x;
    int n   = (f & 7) * 650 + (f >> 3);
    int vi  = n / 1300;
    int rem = n - vi * 1300;
    int b   = rem / 325;
    int tu  = rem - b * 325;

    int tt = tu / 13, ut = tu % 13;
    int t0 = tt * 8, u0 = ut * 8, vb = vi * 256;
    int lane = tid & 63, w = tid >> 6;
    int lrow = lane & 15, kg = lane >> 4;

    int r  = tid >> 2, kc = tid & 3;
    int ta = t0 + (r >> 3);
    int ua = u0 + (r & 7); if (ua > U_ - 1) ua = U_ - 1;
    const unsigned short* eR = encP + ((size_t)b * T_ + ta) * H_ + kc * 8;
    const unsigned short* dR = decP + ((size_t)b * U_ + ua) * H_ + kc * 8;
    int fA = (r >> 1) & 3;

    int pcB = lane & 3;
    const unsigned short* gB[4];
    #pragma unroll
    for (int m = 0; m < 4; ++m) {
        int cl = w * 64 + m * 16 + (lane >> 2);
        gB[m] = Wt + (size_t)(vb + cl) * H_ + (pcB ^ ((cl >> 1) & 3)) * 8;
    }

    f32x4 acc[4][4];
    #pragma unroll
    for (int i = 0; i < 4; ++i)
        #pragma unroll
        for (int j = 0; j < 4; ++j)
            acc[i][j] = (f32x4){0.f, 0.f, 0.f, 0.f};

    {
        uint4 E = *(const uint4*)(eR);
        uint4 D = *(const uint4*)(dR);
        LA[0][r][kc ^ fA] = addrelu16(E, D);
        #pragma unroll
        for (int m = 0; m < 4; ++m)
            gload_lds16(gB[m], &LB[0][w * 64 + m * 16][0]);
    }
    __syncthreads();

    #pragma unroll 2
    for (int kt = 0; kt < 20; ++kt) {
        int cur = kt & 1;
        uint4 En, Dn;
        if (kt < 19) {
            En = *(const uint4*)(eR + (kt + 1) * 32);
            Dn = *(const uint4*)(dR + (kt + 1) * 32);
            #pragma unroll
            for (int m = 0; m < 4; ++m)
                gload_lds16(gB[m] + (kt + 1) * 32, &LB[cur ^ 1][w * 64 + m * 16][0]);
        }
        f16x8 a[4], bq[4];
        #pragma unroll
        for (int i = 0; i < 4; ++i) {
            int row = i * 16 + lrow;
            a[i] = __builtin_bit_cast(f16x8, LA[cur][row][kg ^ ((row >> 1) & 3)]);
        }
        #pragma unroll
        for (int j = 0; j < 4; ++j) {
            int col = w * 64 + j * 16 + lrow;
            bq[j] = __builtin_bit_cast(f16x8, LB[cur][col][kg ^ ((col >> 1) & 3)]);
        }
        #pragma unroll
        for (int i = 0; i < 4; ++i)
            #pragma unroll
            for (int j = 0; j < 4; ++j)
                acc[i][j] = __builtin_amdgcn_mfma_f32_16x16x32_f16(a[i], bq[j], acc[i][j], 0, 0, 0);
        if (kt < 19)
            LA[cur ^ 1][r][kc ^ fA] = addrelu16(En, Dn);
        __syncthreads();
    }

    // ---- epilogue (r17-proven): acc -> LDS [16][ESTR] -> 256B-contiguous scalar stores
    float* etile = (float*)LB;
    #pragma unroll
    for (int i = 0; i < 4; ++i) {
        __syncthreads();
        #pragma unroll
        for (int j = 0; j < 4; ++j) {
            int col = w * 64 + j * 16 + lrow;
            float bo = b_out[vb + col];
            #pragma unroll
            for (int q = 0; q < 4; ++q)
                etile[(kg * 4 + q) * ESTR + col] = acc[i][j][q] + bo;
        }
        __syncthreads();
        #pragma unroll
        for (int rr = 0; rr < 4; ++rr) {
            int row16 = w * 4 + rr;
            int row = i * 16 + row16;
            int t = t0 + (row >> 3);
            int u = u0 + (row & 7);
            if (u < U_) {
                float* ob = &out[(((size_t)b * T_ + t) * U_ + u) * V_ + vb];
                const float* lb = &etile[row16 * ESTR];
                #pragma unroll
                for (int it = 0; it < 4; ++it)
                    ob[it * 64 + lane] = lb[it * 64 + lane];
            }
        }
    }
}

extern "C" void kernel_launch(void* const* d_in, const int* in_sizes, int n_in,
                              void* d_out, int out_size, void* d_ws, size_t ws_size,
                              hipStream_t stream) {
    const float* enc    = (const float*)d_in[0];
    const float* dec    = (const float*)d_in[1];
    const float* W_enc  = (const float*)d_in[2];
    const float* b_enc  = (const float*)d_in[3];
    const float* W_pred = (const float*)d_in[4];
    const float* b_pred = (const float*)d_in[5];
    const float* W_out  = (const float*)d_in[6];
    const float* b_out  = (const float*)d_in[7];
    float* out = (float*)d_out;

    // fp16 buffers: encP 512,000 elems = 1,024,000 B
    char* ws = (char*)d_ws;
    _Float16* encP = (_Float16*)ws;                        // 1,024,000 B
    _Float16* decP = (_Float16*)(ws + 1024000);            //   512,000 B
    _Float16* Wt   = (_Float16*)(ws + 1024000 + 512000);   // 1,474,560 B

    prep_fused_kernel<<<dim3(700), 256, 0, stream>>>(
        enc, W_enc, b_enc, dec, W_pred, b_pred, W_out, encP, decP, Wt);
    joint_kernel<<<dim3(5200 + (B_ * T_ * U_ + 255) / 256), 256, 0, stream>>>(
        (const unsigned short*)encP, (const unsigned short*)decP,
        (const unsigned short*)Wt, b_out, out);
}

// Round 22
// 251.903 us; speedup vs baseline: 1.3252x; 1.0750x over previous
//
#include <hip/hip_runtime.h>
#include <hip/hip_bf16.h>

#define B_   4
#define DENC 512
#define T_   200
#define DDEC 640
#define U_   100
#define H_   640
#define V_   1025
#define VPAD 1152

typedef float f32x4 __attribute__((ext_vector_type(4)));
typedef _Float16 f16x8 __attribute__((ext_vector_type(8)));

// relu(e+d) on 8 packed fp16: 4x v_pk_add_f16 + 4x v_pk_max_f16
__device__ __forceinline__ uint4 addrelu16(uint4 e, uint4 d) {
    f16x8 ev = __builtin_bit_cast(f16x8, e);
    f16x8 dv = __builtin_bit_cast(f16x8, d);
    f16x8 s = ev + dv;
    f16x8 z = {(_Float16)0.f, (_Float16)0.f, (_Float16)0.f, (_Float16)0.f,
               (_Float16)0.f, (_Float16)0.f, (_Float16)0.f, (_Float16)0.f};
    s = __builtin_elementwise_max(s, z);
    return __builtin_bit_cast(uint4, s);
}

__device__ __forceinline__ void gload_lds16(const void* g, void* l) {
    __builtin_amdgcn_global_load_lds(
        (const __attribute__((address_space(1))) unsigned int*)g,
        (__attribute__((address_space(3))) unsigned int*)l, 16, 0, 0);
}

// ---------------- K1: fused prep, wave-split-d version (4x shorter latency chains)
// blocks [0,520): enc   [520,1040): dec   [1040,1220): wt
// enc/dec: block = 64 h-lanes x 4 waves (each wave owns a d-quarter), LDS reduce.
__global__ __launch_bounds__(256) void prep_fused_kernel(
    const float* __restrict__ enc, const float* __restrict__ W_enc,
    const float* __restrict__ b_enc,
    const float* __restrict__ dec, const float* __restrict__ W_pred,
    const float* __restrict__ b_pred,
    const float* __restrict__ W_out,
    _Float16* __restrict__ encP, _Float16* __restrict__ decP,
    _Float16* __restrict__ Wt)
{
    __shared__ float sbuf[4224];               // enc: [4][16][66]; dec: [4][8][66]; wt: [64][65]
    int bx = blockIdx.x;
    int tid = threadIdx.x;
    int lane = tid & 63, w = tid >> 6;

    if (bx < 520) {
        // ---- enc_proj: b = bx/130; hc = (bx%130)/13; tg = (bx%130)%13
        int b = bx / 130, r5 = bx % 130, hc = r5 / 13, tg = r5 % 13;
        int h  = hc * 64 + lane;
        int t0 = tg * 16;
        const float* Wc = W_enc + h;
        const float* ec = enc + (size_t)b * DENC * T_ + t0;
        int d0 = w * 128;                      // wave's d-quarter
        float acc[16];
        #pragma unroll
        for (int i = 0; i < 16; ++i) acc[i] = 0.f;
        if (t0 + 16 <= T_) {
            #pragma unroll 8
            for (int i = 0; i < 128; ++i) {
                int d = d0 + i;
                float wv = Wc[(size_t)d * H_];
                const float* p = ec + (size_t)d * T_;
                float4 a0 = *(const float4*)(p);
                float4 a1 = *(const float4*)(p + 4);
                float4 a2 = *(const float4*)(p + 8);
                float4 a3 = *(const float4*)(p + 12);
                acc[0]+=wv*a0.x; acc[1]+=wv*a0.y; acc[2]+=wv*a0.z; acc[3]+=wv*a0.w;
                acc[4]+=wv*a1.x; acc[5]+=wv*a1.y; acc[6]+=wv*a1.z; acc[7]+=wv*a1.w;
                acc[8]+=wv*a2.x; acc[9]+=wv*a2.y; acc[10]+=wv*a2.z; acc[11]+=wv*a2.w;
                acc[12]+=wv*a3.x; acc[13]+=wv*a3.y; acc[14]+=wv*a3.z; acc[15]+=wv*a3.w;
            }
        } else {                               // tg=12: t 192..199 (8 valid)
            #pragma unroll 8
            for (int i = 0; i < 128; ++i) {
                int d = d0 + i;
                float wv = Wc[(size_t)d * H_];
                const float* p = ec + (size_t)d * T_;
                float4 a0 = *(const float4*)(p);
                float4 a1 = *(const float4*)(p + 4);
                acc[0]+=wv*a0.x; acc[1]+=wv*a0.y; acc[2]+=wv*a0.z; acc[3]+=wv*a0.w;
                acc[4]+=wv*a1.x; acc[5]+=wv*a1.y; acc[6]+=wv*a1.z; acc[7]+=wv*a1.w;
            }
        }
        #pragma unroll
        for (int t = 0; t < 16; ++t)
            sbuf[(w * 16 + t) * 66 + lane] = acc[t];
        __syncthreads();
        #pragma unroll
        for (int k = 0; k < 4; ++k) {
            int oi = tid + k * 256;
            int t = oi >> 6, hl = oi & 63;
            if (t0 + t < T_) {
                float s = sbuf[(0 * 16 + t) * 66 + hl] + sbuf[(1 * 16 + t) * 66 + hl]
                        + sbuf[(2 * 16 + t) * 66 + hl] + sbuf[(3 * 16 + t) * 66 + hl]
                        + b_enc[hc * 64 + hl];
                encP[((size_t)b * T_ + t0 + t) * H_ + hc * 64 + hl] = (_Float16)s;
            }
        }
    } else if (bx < 1040) {
        // ---- dec_proj: same structure, d-quarter = 160
        int i5 = bx - 520;
        int b = i5 / 130, r5 = i5 % 130, hc = r5 / 13, ug = r5 % 13;
        int h  = hc * 64 + lane;
        int u0 = ug * 8;
        const float* Wc = W_pred + h;
        const float* dc = dec + (size_t)b * DDEC * U_ + u0;
        int d0 = w * 160;
        float acc[8];
        #pragma unroll
        for (int i = 0; i < 8; ++i) acc[i] = 0.f;
        if (u0 + 8 <= U_) {
            #pragma unroll 8
            for (int i = 0; i < 160; ++i) {
                int d = d0 + i;
                float wv = Wc[(size_t)d * H_];
                const float* p = dc + (size_t)d * U_;
                float4 a0 = *(const float4*)(p);
                float4 a1 = *(const float4*)(p + 4);
                acc[0]+=wv*a0.x; acc[1]+=wv*a0.y; acc[2]+=wv*a0.z; acc[3]+=wv*a0.w;
                acc[4]+=wv*a1.x; acc[5]+=wv*a1.y; acc[6]+=wv*a1.z; acc[7]+=wv*a1.w;
            }
        } else {                               // ug=12: u 96..99 (4 valid)
            #pragma unroll 8
            for (int i = 0; i < 160; ++i) {
                int d = d0 + i;
                float wv = Wc[(size_t)d * H_];
                const float* p = dc + (size_t)d * U_;
                float4 a0 = *(const float4*)(p);
                acc[0]+=wv*a0.x; acc[1]+=wv*a0.y; acc[2]+=wv*a0.z; acc[3]+=wv*a0.w;
            }
        }
        #pragma unroll
        for (int u = 0; u < 8; ++u)
            sbuf[(w * 8 + u) * 66 + lane] = acc[u];
        __syncthreads();
        #pragma unroll
        for (int k = 0; k < 2; ++k) {
            int oi = tid + k * 256;
            int u = oi >> 6, hl = oi & 63;
            if (u0 + u < U_) {
                float s = sbuf[(0 * 8 + u) * 66 + hl] + sbuf[(1 * 8 + u) * 66 + hl]
                        + sbuf[(2 * 8 + u) * 66 + hl] + sbuf[(3 * 8 + u) * 66 + hl]
                        + b_pred[hc * 64 + hl];
                decP[((size_t)b * U_ + u0 + u) * H_ + hc * 64 + hl] = (_Float16)s;
            }
        }
    } else {
        // ---- wt_transpose: Wt[v][h] = fp16(W_out[h][v]) (v padded to VPAD with 0)
        int j = bx - 1040;
        int hc = j / 18, vc = j % 18;
        int h0 = hc * 64, v0 = vc * 64;
        float (*tile)[65] = (float(*)[65])sbuf;
        #pragma unroll
        for (int it = 0; it < 16; ++it) {
            int hl = it * 4 + (tid >> 6);
            int vl = tid & 63;
            int v = v0 + vl;
            tile[hl][vl] = (v < V_) ? W_out[(size_t)(h0 + hl) * V_ + v] : 0.f;
        }
        __syncthreads();
        #pragma unroll
        for (int it = 0; it < 16; ++it) {
            int vl = it * 4 + (tid >> 6);
            int hl = tid & 63;
            Wt[(size_t)(v0 + vl) * H_ + h0 + hl] = (_Float16)tile[hl][vl];
        }
    }
}

// ---------------- K4: r18/r21 champion joint (UNCHANGED, proven ~200us)
// blocks [0,5200): GEMM tiles.  blocks [5200,5513): v=1024 column.
#define ESTR 260
__global__ __launch_bounds__(256) void joint_kernel(
    const unsigned short* __restrict__ encP,   // [B,T,H] fp16
    const unsigned short* __restrict__ decP,   // [B,U,H] fp16
    const unsigned short* __restrict__ Wt,     // [VPAD][H] fp16
    const float* __restrict__ b_out,           // [V]
    float* __restrict__ out)                   // [B,T,U,V] f32
{
    __shared__ uint4 LA[2][64][4];             // 8 KB
    __shared__ uint4 LB[2][256][4];            // 32 KB
    int tid = threadIdx.x;

    if (blockIdx.x >= 5200) {
        int idx = (blockIdx.x - 5200) * 256 + tid;
        if (idx >= B_ * T_ * U_) return;
        int u = idx % U_;
        int t = (idx / U_) % T_;
        int b = idx / (U_ * T_);
        const uint4* e = (const uint4*)(encP + ((size_t)b * T_ + t) * H_);
        const uint4* d = (const uint4*)(decP + ((size_t)b * U_ + u) * H_);
        const uint4* wv = (const uint4*)(Wt + (size_t)1024 * H_);
        float acc1 = 0.f;
        for (int c = 0; c < H_ / 8; ++c) {
            f16x8 x = __builtin_bit_cast(f16x8, addrelu16(e[c], d[c]));
            f16x8 wq = __builtin_bit_cast(f16x8, wv[c]);
            #pragma unroll
            for (int m = 0; m < 8; ++m)
                acc1 += (float)x[m] * (float)wq[m];
        }
        out[((size_t)(b * T_ + t) * U_ + u) * V_ + 1024] = acc1 + b_out[1024];
        return;
    }

    int f   = blockIdx.x;
    int n   = (f & 7) * 650 + (f >> 3);
    int vi  = n / 1300;
    int rem = n - vi * 1300;
    int b   = rem / 325;
    int tu  = rem - b * 325;

    int tt = tu / 13, ut = tu % 13;
    int t0 = tt * 8, u0 = ut * 8, vb = vi * 256;
    int lane = tid & 63, w = tid >> 6;
    int lrow = lane & 15, kg = lane >> 4;

    int r  = tid >> 2, kc = tid & 3;
    int ta = t0 + (r >> 3);
    int ua = u0 + (r & 7); if (ua > U_ - 1) ua = U_ - 1;
    const unsigned short* eR = encP + ((size_t)b * T_ + ta) * H_ + kc * 8;
    const unsigned short* dR = decP + ((size_t)b * U_ + ua) * H_ + kc * 8;
    int fA = (r >> 1) & 3;

    int pcB = lane & 3;
    const unsigned short* gB[4];
    #pragma unroll
    for (int m = 0; m < 4; ++m) {
        int cl = w * 64 + m * 16 + (lane >> 2);
        gB[m] = Wt + (size_t)(vb + cl) * H_ + (pcB ^ ((cl >> 1) & 3)) * 8;
    }

    f32x4 acc[4][4];
    #pragma unroll
    for (int i = 0; i < 4; ++i)
        #pragma unroll
        for (int j = 0; j < 4; ++j)
            acc[i][j] = (f32x4){0.f, 0.f, 0.f, 0.f};

    {
        uint4 E = *(const uint4*)(eR);
        uint4 D = *(const uint4*)(dR);
        LA[0][r][kc ^ fA] = addrelu16(E, D);
        #pragma unroll
        for (int m = 0; m < 4; ++m)
            gload_lds16(gB[m], &LB[0][w * 64 + m * 16][0]);
    }
    __syncthreads();

    #pragma unroll 2
    for (int kt = 0; kt < 20; ++kt) {
        int cur = kt & 1;
        uint4 En, Dn;
        if (kt < 19) {
            En = *(const uint4*)(eR + (kt + 1) * 32);
            Dn = *(const uint4*)(dR + (kt + 1) * 32);
            #pragma unroll
            for (int m = 0; m < 4; ++m)
                gload_lds16(gB[m] + (kt + 1) * 32, &LB[cur ^ 1][w * 64 + m * 16][0]);
        }
        f16x8 a[4], bq[4];
        #pragma unroll
        for (int i = 0; i < 4; ++i) {
            int row = i * 16 + lrow;
            a[i] = __builtin_bit_cast(f16x8, LA[cur][row][kg ^ ((row >> 1) & 3)]);
        }
        #pragma unroll
        for (int j = 0; j < 4; ++j) {
            int col = w * 64 + j * 16 + lrow;
            bq[j] = __builtin_bit_cast(f16x8, LB[cur][col][kg ^ ((col >> 1) & 3)]);
        }
        #pragma unroll
        for (int i = 0; i < 4; ++i)
            #pragma unroll
            for (int j = 0; j < 4; ++j)
                acc[i][j] = __builtin_amdgcn_mfma_f32_16x16x32_f16(a[i], bq[j], acc[i][j], 0, 0, 0);
        if (kt < 19)
            LA[cur ^ 1][r][kc ^ fA] = addrelu16(En, Dn);
        __syncthreads();
    }

    float* etile = (float*)LB;
    #pragma unroll
    for (int i = 0; i < 4; ++i) {
        __syncthreads();
        #pragma unroll
        for (int j = 0; j < 4; ++j) {
            int col = w * 64 + j * 16 + lrow;
            float bo = b_out[vb + col];
            #pragma unroll
            for (int q = 0; q < 4; ++q)
                etile[(kg * 4 + q) * ESTR + col] = acc[i][j][q] + bo;
        }
        __syncthreads();
        #pragma unroll
        for (int rr = 0; rr < 4; ++rr) {
            int row16 = w * 4 + rr;
            int row = i * 16 + row16;
            int t = t0 + (row >> 3);
            int u = u0 + (row & 7);
            if (u < U_) {
                float* ob = &out[(((size_t)b * T_ + t) * U_ + u) * V_ + vb];
                const float* lb = &etile[row16 * ESTR];
                #pragma unroll
                for (int it = 0; it < 4; ++it)
                    ob[it * 64 + lane] = lb[it * 64 + lane];
            }
        }
    }
}

extern "C" void kernel_launch(void* const* d_in, const int* in_sizes, int n_in,
                              void* d_out, int out_size, void* d_ws, size_t ws_size,
                              hipStream_t stream) {
    const float* enc    = (const float*)d_in[0];
    const float* dec    = (const float*)d_in[1];
    const float* W_enc  = (const float*)d_in[2];
    const float* b_enc  = (const float*)d_in[3];
    const float* W_pred = (const float*)d_in[4];
    const float* b_pred = (const float*)d_in[5];
    const float* W_out  = (const float*)d_in[6];
    const float* b_out  = (const float*)d_in[7];
    float* out = (float*)d_out;

    // fp16 buffers: encP 512,000 elems = 1,024,000 B
    char* ws = (char*)d_ws;
    _Float16* encP = (_Float16*)ws;                        // 1,024,000 B
    _Float16* decP = (_Float16*)(ws + 1024000);            //   512,000 B
    _Float16* Wt   = (_Float16*)(ws + 1024000 + 512000);   // 1,474,560 B

    prep_fused_kernel<<<dim3(1220), 256, 0, stream>>>(
        enc, W_enc, b_enc, dec, W_pred, b_pred, W_out, encP, decP, Wt);
    joint_kernel<<<dim3(5200 + (B_ * T_ * U_ + 255) / 256), 256, 0, stream>>>(
        (const unsigned short*)encP, (const unsigned short*)decP,
        (const unsigned short*)Wt, b_out, out);
}

// Round 23
// 235.456 us; speedup vs baseline: 1.4177x; 1.0699x over previous
//
#include <hip/hip_runtime.h>
#include <hip/hip_bf16.h>

#define B_   4
#define DENC 512
#define T_   200
#define DDEC 640
#define U_   100
#define H_   640
#define V_   1025
#define VPAD 1152

typedef float f32x4 __attribute__((ext_vector_type(4)));
typedef _Float16 f16x8 __attribute__((ext_vector_type(8)));

// relu(e+d) on 8 packed fp16: 4x v_pk_add_f16 + 4x v_pk_max_f16
__device__ __forceinline__ uint4 addrelu16(uint4 e, uint4 d) {
    f16x8 ev = __builtin_bit_cast(f16x8, e);
    f16x8 dv = __builtin_bit_cast(f16x8, d);
    f16x8 s = ev + dv;
    f16x8 z = {(_Float16)0.f, (_Float16)0.f, (_Float16)0.f, (_Float16)0.f,
               (_Float16)0.f, (_Float16)0.f, (_Float16)0.f, (_Float16)0.f};
    s = __builtin_elementwise_max(s, z);
    return __builtin_bit_cast(uint4, s);
}

__device__ __forceinline__ void gload_lds16(const void* g, void* l) {
    __builtin_amdgcn_global_load_lds(
        (const __attribute__((address_space(1))) unsigned int*)g,
        (__attribute__((address_space(3))) unsigned int*)l, 16, 0, 0);
}

// ---------------- K1: fused prep, 512 threads / 8-way wave-split-d (chains 64/80)
// blocks [0,520): enc   [520,1040): dec   [1040,1220): wt
__global__ __launch_bounds__(512) void prep_fused_kernel(
    const float* __restrict__ enc, const float* __restrict__ W_enc,
    const float* __restrict__ b_enc,
    const float* __restrict__ dec, const float* __restrict__ W_pred,
    const float* __restrict__ b_pred,
    const float* __restrict__ W_out,
    _Float16* __restrict__ encP, _Float16* __restrict__ decP,
    _Float16* __restrict__ Wt)
{
    __shared__ float sbuf[8448];               // enc: [8][16][66]=33.8KB; dec: [8][8][66]; wt: [64][65]
    int bx = blockIdx.x;
    int tid = threadIdx.x;
    int lane = tid & 63, w = tid >> 6;         // 8 waves

    if (bx < 520) {
        // ---- enc_proj: b = bx/130; hc = (bx%130)/13; tg = (bx%130)%13
        int b = bx / 130, r5 = bx % 130, hc = r5 / 13, tg = r5 % 13;
        int h  = hc * 64 + lane;
        int t0 = tg * 16;
        const float* Wc = W_enc + h;
        const float* ec = enc + (size_t)b * DENC * T_ + t0;
        int d0 = w * 64;                       // wave's d-eighth
        float acc[16];
        #pragma unroll
        for (int i = 0; i < 16; ++i) acc[i] = 0.f;
        if (t0 + 16 <= T_) {
            #pragma unroll 8
            for (int i = 0; i < 64; ++i) {
                int d = d0 + i;
                float wv = Wc[(size_t)d * H_];
                const float* p = ec + (size_t)d * T_;
                float4 a0 = *(const float4*)(p);
                float4 a1 = *(const float4*)(p + 4);
                float4 a2 = *(const float4*)(p + 8);
                float4 a3 = *(const float4*)(p + 12);
                acc[0]+=wv*a0.x; acc[1]+=wv*a0.y; acc[2]+=wv*a0.z; acc[3]+=wv*a0.w;
                acc[4]+=wv*a1.x; acc[5]+=wv*a1.y; acc[6]+=wv*a1.z; acc[7]+=wv*a1.w;
                acc[8]+=wv*a2.x; acc[9]+=wv*a2.y; acc[10]+=wv*a2.z; acc[11]+=wv*a2.w;
                acc[12]+=wv*a3.x; acc[13]+=wv*a3.y; acc[14]+=wv*a3.z; acc[15]+=wv*a3.w;
            }
        } else {                               // tg=12: t 192..199 (8 valid)
            #pragma unroll 8
            for (int i = 0; i < 64; ++i) {
                int d = d0 + i;
                float wv = Wc[(size_t)d * H_];
                const float* p = ec + (size_t)d * T_;
                float4 a0 = *(const float4*)(p);
                float4 a1 = *(const float4*)(p + 4);
                acc[0]+=wv*a0.x; acc[1]+=wv*a0.y; acc[2]+=wv*a0.z; acc[3]+=wv*a0.w;
                acc[4]+=wv*a1.x; acc[5]+=wv*a1.y; acc[6]+=wv*a1.z; acc[7]+=wv*a1.w;
            }
        }
        #pragma unroll
        for (int t = 0; t < 16; ++t)
            sbuf[(w * 16 + t) * 66 + lane] = acc[t];
        __syncthreads();
        #pragma unroll
        for (int k = 0; k < 2; ++k) {
            int oi = tid + k * 512;
            int t = oi >> 6, hl = oi & 63;
            if (t0 + t < T_) {
                float s = 0.f;
                #pragma unroll
                for (int ww = 0; ww < 8; ++ww)
                    s += sbuf[(ww * 16 + t) * 66 + hl];
                s += b_enc[hc * 64 + hl];
                encP[((size_t)b * T_ + t0 + t) * H_ + hc * 64 + hl] = (_Float16)s;
            }
        }
    } else if (bx < 1040) {
        // ---- dec_proj: same structure, d-eighth = 80
        int i5 = bx - 520;
        int b = i5 / 130, r5 = i5 % 130, hc = r5 / 13, ug = r5 % 13;
        int h  = hc * 64 + lane;
        int u0 = ug * 8;
        const float* Wc = W_pred + h;
        const float* dc = dec + (size_t)b * DDEC * U_ + u0;
        int d0 = w * 80;
        float acc[8];
        #pragma unroll
        for (int i = 0; i < 8; ++i) acc[i] = 0.f;
        if (u0 + 8 <= U_) {
            #pragma unroll 8
            for (int i = 0; i < 80; ++i) {
                int d = d0 + i;
                float wv = Wc[(size_t)d * H_];
                const float* p = dc + (size_t)d * U_;
                float4 a0 = *(const float4*)(p);
                float4 a1 = *(const float4*)(p + 4);
                acc[0]+=wv*a0.x; acc[1]+=wv*a0.y; acc[2]+=wv*a0.z; acc[3]+=wv*a0.w;
                acc[4]+=wv*a1.x; acc[5]+=wv*a1.y; acc[6]+=wv*a1.z; acc[7]+=wv*a1.w;
            }
        } else {                               // ug=12: u 96..99 (4 valid)
            #pragma unroll 8
            for (int i = 0; i < 80; ++i) {
                int d = d0 + i;
                float wv = Wc[(size_t)d * H_];
                const float* p = dc + (size_t)d * U_;
                float4 a0 = *(const float4*)(p);
                acc[0]+=wv*a0.x; acc[1]+=wv*a0.y; acc[2]+=wv*a0.z; acc[3]+=wv*a0.w;
            }
        }
        #pragma unroll
        for (int u = 0; u < 8; ++u)
            sbuf[(w * 8 + u) * 66 + lane] = acc[u];
        __syncthreads();
        {
            int u = tid >> 6, hl = tid & 63;
            if (u0 + u < U_) {
                float s = 0.f;
                #pragma unroll
                for (int ww = 0; ww < 8; ++ww)
                    s += sbuf[(ww * 8 + u) * 66 + hl];
                s += b_pred[hc * 64 + hl];
                decP[((size_t)b * U_ + u0 + u) * H_ + hc * 64 + hl] = (_Float16)s;
            }
        }
    } else {
        // ---- wt_transpose: Wt[v][h] = fp16(W_out[h][v]) (v padded to VPAD with 0)
        int j = bx - 1040;
        int hc = j / 18, vc = j % 18;
        int h0 = hc * 64, v0 = vc * 64;
        float (*tile)[65] = (float(*)[65])sbuf;
        #pragma unroll
        for (int it = 0; it < 8; ++it) {
            int hl = it * 8 + (tid >> 6);
            int vl = tid & 63;
            int v = v0 + vl;
            tile[hl][vl] = (v < V_) ? W_out[(size_t)(h0 + hl) * V_ + v] : 0.f;
        }
        __syncthreads();
        #pragma unroll
        for (int it = 0; it < 8; ++it) {
            int vl = it * 8 + (tid >> 6);
            int hl = tid & 63;
            Wt[(size_t)(v0 + vl) * H_ + h0 + hl] = (_Float16)tile[hl][vl];
        }
    }
}

// ---------------- K4: r18/r21 champion joint + min-occupancy hint (4 blocks/CU)
// blocks [0,5200): GEMM tiles.  blocks [5200,5513): v=1024 column.
#define ESTR 260
__global__ __launch_bounds__(256, 4) void joint_kernel(
    const unsigned short* __restrict__ encP,   // [B,T,H] fp16
    const unsigned short* __restrict__ decP,   // [B,U,H] fp16
    const unsigned short* __restrict__ Wt,     // [VPAD][H] fp16
    const float* __restrict__ b_out,           // [V]
    float* __restrict__ out)                   // [B,T,U,V] f32
{
    __shared__ uint4 LA[2][64][4];             // 8 KB
    __shared__ uint4 LB[2][256][4];            // 32 KB
    int tid = threadIdx.x;

    if (blockIdx.x >= 5200) {
        int idx = (blockIdx.x - 5200) * 256 + tid;
        if (idx >= B_ * T_ * U_) return;
        int u = idx % U_;
        int t = (idx / U_) % T_;
        int b = idx / (U_ * T_);
        const uint4* e = (const uint4*)(encP + ((size_t)b * T_ + t) * H_);
        const uint4* d = (const uint4*)(decP + ((size_t)b * U_ + u) * H_);
        const uint4* wv = (const uint4*)(Wt + (size_t)1024 * H_);
        float acc1 = 0.f;
        for (int c = 0; c < H_ / 8; ++c) {
            f16x8 x = __builtin_bit_cast(f16x8, addrelu16(e[c], d[c]));
            f16x8 wq = __builtin_bit_cast(f16x8, wv[c]);
            #pragma unroll
            for (int m = 0; m < 8; ++m)
                acc1 += (float)x[m] * (float)wq[m];
        }
        out[((size_t)(b * T_ + t) * U_ + u) * V_ + 1024] = acc1 + b_out[1024];
        return;
    }

    int f   = blockIdx.x;
    int n   = (f & 7) * 650 + (f >> 3);
    int vi  = n / 1300;
    int rem = n - vi * 1300;
    int b   = rem / 325;
    int tu  = rem - b * 325;

    int tt = tu / 13, ut = tu % 13;
    int t0 = tt * 8, u0 = ut * 8, vb = vi * 256;
    int lane = tid & 63, w = tid >> 6;
    int lrow = lane & 15, kg = lane >> 4;

    int r  = tid >> 2, kc = tid & 3;
    int ta = t0 + (r >> 3);
    int ua = u0 + (r & 7); if (ua > U_ - 1) ua = U_ - 1;
    const unsigned short* eR = encP + ((size_t)b * T_ + ta) * H_ + kc * 8;
    const unsigned short* dR = decP + ((size_t)b * U_ + ua) * H_ + kc * 8;
    int fA = (r >> 1) & 3;

    int pcB = lane & 3;
    const unsigned short* gB[4];
    #pragma unroll
    for (int m = 0; m < 4; ++m) {
        int cl = w * 64 + m * 16 + (lane >> 2);
        gB[m] = Wt + (size_t)(vb + cl) * H_ + (pcB ^ ((cl >> 1) & 3)) * 8;
    }

    f32x4 acc[4][4];
    #pragma unroll
    for (int i = 0; i < 4; ++i)
        #pragma unroll
        for (int j = 0; j < 4; ++j)
            acc[i][j] = (f32x4){0.f, 0.f, 0.f, 0.f};

    {
        uint4 E = *(const uint4*)(eR);
        uint4 D = *(const uint4*)(dR);
        LA[0][r][kc ^ fA] = addrelu16(E, D);
        #pragma unroll
        for (int m = 0; m < 4; ++m)
            gload_lds16(gB[m], &LB[0][w * 64 + m * 16][0]);
    }
    __syncthreads();

    #pragma unroll 2
    for (int kt = 0; kt < 20; ++kt) {
        int cur = kt & 1;
        uint4 En, Dn;
        if (kt < 19) {
            En = *(const uint4*)(eR + (kt + 1) * 32);
            Dn = *(const uint4*)(dR + (kt + 1) * 32);
            #pragma unroll
            for (int m = 0; m < 4; ++m)
                gload_lds16(gB[m] + (kt + 1) * 32, &LB[cur ^ 1][w * 64 + m * 16][0]);
        }
        f16x8 a[4], bq[4];
        #pragma unroll
        for (int i = 0; i < 4; ++i) {
            int row = i * 16 + lrow;
            a[i] = __builtin_bit_cast(f16x8, LA[cur][row][kg ^ ((row >> 1) & 3)]);
        }
        #pragma unroll
        for (int j = 0; j < 4; ++j) {
            int col = w * 64 + j * 16 + lrow;
            bq[j] = __builtin_bit_cast(f16x8, LB[cur][col][kg ^ ((col >> 1) & 3)]);
        }
        #pragma unroll
        for (int i = 0; i < 4; ++i)
            #pragma unroll
            for (int j = 0; j < 4; ++j)
                acc[i][j] = __builtin_amdgcn_mfma_f32_16x16x32_f16(a[i], bq[j], acc[i][j], 0, 0, 0);
        if (kt < 19)
            LA[cur ^ 1][r][kc ^ fA] = addrelu16(En, Dn);
        __syncthreads();
    }

    float* etile = (float*)LB;
    #pragma unroll
    for (int i = 0; i < 4; ++i) {
        __syncthreads();
        #pragma unroll
        for (int j = 0; j < 4; ++j) {
            int col = w * 64 + j * 16 + lrow;
            float bo = b_out[vb + col];
            #pragma unroll
            for (int q = 0; q < 4; ++q)
                etile[(kg * 4 + q) * ESTR + col] = acc[i][j][q] + bo;
        }
        __syncthreads();
        #pragma unroll
        for (int rr = 0; rr < 4; ++rr) {
            int row16 = w * 4 + rr;
            int row = i * 16 + row16;
            int t = t0 + (row >> 3);
            int u = u0 + (row & 7);
            if (u < U_) {
                float* ob = &out[(((size_t)b * T_ + t) * U_ + u) * V_ + vb];
                const float* lb = &etile[row16 * ESTR];
                #pragma unroll
                for (int it = 0; it < 4; ++it)
                    ob[it * 64 + lane] = lb[it * 64 + lane];
            }
        }
    }
}

extern "C" void kernel_launch(void* const* d_in, const int* in_sizes, int n_in,
                              void* d_out, int out_size, void* d_ws, size_t ws_size,
                              hipStream_t stream) {
    const float* enc    = (const float*)d_in[0];
    const float* dec    = (const float*)d_in[1];
    const float* W_enc  = (const float*)d_in[2];
    const float* b_enc  = (const float*)d_in[3];
    const float* W_pred = (const float*)d_in[4];
    const float* b_pred = (const float*)d_in[5];
    const float* W_out  = (const float*)d_in[6];
    const float* b_out  = (const float*)d_in[7];
    float* out = (float*)d_out;

    // fp16 buffers: encP 512,000 elems = 1,024,000 B
    char* ws = (char*)d_ws;
    _Float16* encP = (_Float16*)ws;                        // 1,024,000 B
    _Float16* decP = (_Float16*)(ws + 1024000);            //   512,000 B
    _Float16* Wt   = (_Float16*)(ws + 1024000 + 512000);   // 1,474,560 B

    prep_fused_kernel<<<dim3(1220), 512, 0, stream>>>(
        enc, W_enc, b_enc, dec, W_pred, b_pred, W_out, encP, decP, Wt);
    joint_kernel<<<dim3(5200 + (B_ * T_ * U_ + 255) / 256), 256, 0, stream>>>(
        (const unsigned short*)encP, (const unsigned short*)decP,
        (const unsigned short*)Wt, b_out, out);
}